// Round 9
// baseline (786.715 us; speedup 1.0000x reference)
//
#include <hip/hip_runtime.h>
#include <cmath>

#define TT 256
#define BB 512
#define DD 128
#define HH 128
#define NCOL 528   // 4*H + 16 quantum-angle cols
#define KK 256
#define NCPAD 576  // 9 * 64

// ---------------- weight pack ----------------
// Wxp[528][128]                 : x-half row-major (xgemm staging)
// Whr3 float4[j][t] (j=g*8+k4)  : h-half main cols; thread t=h*4+ks owns cols
//                                 {g*128+h, g=0..3}, k-seg ks (32 k each)
//                                 rec keeps j<20 in VGPR, j>=20 in LDS
// Whql[16][128]                 : h-half quantum cols (staged to LDS in rec)
// bcat[576]
__global__ __launch_bounds__(256) void pack_weights(
    const float* __restrict__ Wf, const float* __restrict__ bf,
    const float* __restrict__ Wfq, const float* __restrict__ bfq,
    const float* __restrict__ Wi, const float* __restrict__ bi,
    const float* __restrict__ Wiq, const float* __restrict__ biq,
    const float* __restrict__ Wg, const float* __restrict__ bg,
    const float* __restrict__ Wgq, const float* __restrict__ bgq,
    const float* __restrict__ Wo, const float* __restrict__ bo,
    const float* __restrict__ Woq, const float* __restrict__ boq,
    float* __restrict__ Wxp, float* __restrict__ Whr3,
    float* __restrict__ Whql, float* __restrict__ bcat)
{
    int idx = blockIdx.x * blockDim.x + threadIdx.x;
    if (idx < NCOL * KK) {
        int c = idx >> 8, k = idx & 255;
        const float* srcW; int cl;
        if (c < 512) { int g = c >> 7; cl = c & 127;
            srcW = (g == 0) ? Wf : (g == 1) ? Wi : (g == 2) ? Wg : Wo; }
        else { int g = (c - 512) >> 2; cl = (c - 512) & 3;
            srcW = (g == 0) ? Wfq : (g == 1) ? Wiq : (g == 2) ? Wgq : Woq; }
        float v = srcW[(size_t)cl * KK + k];
        if (k < 128) Wxp[(size_t)c * 128 + k] = v;
        else {
            int kk = k - 128;
            if (c < 512) {
                int gate = c >> 7, hcol = c & 127;
                int t = hcol * 4 + (kk >> 5);
                int j = gate * 8 + ((kk >> 2) & 7);
                Whr3[((size_t)j * 512 + t) * 4 + (kk & 3)] = v;
            } else {
                Whql[(size_t)(c - 512) * 128 + kk] = v;
            }
        }
    }
    if (idx < NCPAD) {
        float b = 0.f;
        int c = idx;
        if (c < 512) { int g = c >> 7; int cl = c & 127;
            b = (g == 0) ? bf[cl] : (g == 1) ? bi[cl] : (g == 2) ? bg[cl] : bo[cl]; }
        else if (c < NCOL) { int g = (c - 512) >> 2; int cl = (c - 512) & 3;
            b = (g == 0) ? bfq[cl] : (g == 1) ? biq[cl] : (g == 2) ? bgq[cl] : boq[cl]; }
        bcat[c] = b;
    }
}

// ---------------- phase 1: Zx = X @ Wx^T + bcat  (M x 528, K=128) ----------------
#define P1_BM 128
#define P1_BN 64
#define ATP 132
#define BTP 68
__global__ __launch_bounds__(256, 3) void xgemm(
    const float* __restrict__ X, const float* __restrict__ Wxp,
    const float* __restrict__ bcat, float* __restrict__ Zx)
{
    __shared__ float At[64][ATP];
    __shared__ float Bt[64][BTP];
    const int tid = threadIdx.x;
    const int m0 = blockIdx.x * P1_BM;
    const int c0 = blockIdx.y * P1_BN;
    const int tm = tid >> 3;
    const int tn = tid & 7;
    float acc[4][8] = {};

    for (int khf = 0; khf < 2; ++khf) {
        #pragma unroll
        for (int j = 0; j < 8; ++j) {
            int fidx = tid + 256 * j;
            int m = fidx >> 4, k4 = (fidx & 15) * 4;
            float4 v = *(const float4*)(X + (size_t)(m0 + m) * 128 + khf * 64 + k4);
            At[k4 + 0][m] = v.x; At[k4 + 1][m] = v.y; At[k4 + 2][m] = v.z; At[k4 + 3][m] = v.w;
        }
        #pragma unroll
        for (int j = 0; j < 4; ++j) {
            int fidx = tid + 256 * j;
            int c = fidx >> 4, k4 = (fidx & 15) * 4;
            int cg = c0 + c;
            float4 v = make_float4(0.f, 0.f, 0.f, 0.f);
            if (cg < NCOL) v = *(const float4*)(Wxp + (size_t)cg * 128 + khf * 64 + k4);
            Bt[k4 + 0][c] = v.x; Bt[k4 + 1][c] = v.y; Bt[k4 + 2][c] = v.z; Bt[k4 + 3][c] = v.w;
        }
        __syncthreads();
        #pragma unroll 4
        for (int k = 0; k < 64; ++k) {
            float4 a  = *(const float4*)&At[k][tm * 4];
            float4 b0 = *(const float4*)&Bt[k][tn * 8];
            float4 b1 = *(const float4*)&Bt[k][tn * 8 + 4];
            float av[4] = {a.x, a.y, a.z, a.w};
            float bv[8] = {b0.x, b0.y, b0.z, b0.w, b1.x, b1.y, b1.z, b1.w};
            #pragma unroll
            for (int i = 0; i < 4; ++i)
                #pragma unroll
                for (int j = 0; j < 8; ++j)
                    acc[i][j] = fmaf(av[i], bv[j], acc[i][j]);
        }
        __syncthreads();
    }
    int c = c0 + tn * 8;
    if (c < NCOL) {
        float4 ba = *(const float4*)(bcat + c);
        float4 bb = *(const float4*)(bcat + c + 4);
        #pragma unroll
        for (int i = 0; i < 4; ++i) {
            int m = m0 + tm * 4 + i;
            float4 o0, o1;
            o0.x = acc[i][0] + ba.x; o0.y = acc[i][1] + ba.y;
            o0.z = acc[i][2] + ba.z; o0.w = acc[i][3] + ba.w;
            o1.x = acc[i][4] + bb.x; o1.y = acc[i][5] + bb.y;
            o1.z = acc[i][6] + bb.z; o1.w = acc[i][7] + bb.w;
            *(float4*)(Zx + (size_t)m * NCOL + c)     = o0;
            *(float4*)(Zx + (size_t)m * NCOL + c + 4) = o1;
        }
    }
}

// ---------------- phase 2: recurrence ----------------
__device__ __forceinline__ float sigm(float x) { return 1.0f / (1.0f + __expf(-x)); }
__device__ __forceinline__ float tanh_f(float x) {
    float e = __expf(2.f * x);
    return 1.f - 2.f / (e + 1.f);
}

// macro params must NOT be named x/y/z/w
#define FMA4(acc, Wv, Xv) acc = fmaf((Wv).x, (Xv).x, fmaf((Wv).y, (Xv).y, fmaf((Wv).z, (Xv).z, fmaf((Wv).w, (Xv).w, (acc)))))
#define PIN4(Wv) asm volatile("" : "+v"((Wv).x), "+v"((Wv).y), "+v"((Wv).z), "+v"((Wv).w))

// skewed h index: the 4 k-segments land on distinct bank quads
__device__ __forceinline__ int hsk(int k) { return k + 8 * (k >> 5); }  // max 151

// 512 threads; waves_per_eu(2,2): 256-VGPR cap. Weights: 20 f4 VGPR + 12 f4 LDS.
__global__ __launch_bounds__(512)
__attribute__((amdgpu_waves_per_eu(2, 2)))
void qlstm_rec(
    const float* __restrict__ Zx,      // [TC][512][528]
    const float* __restrict__ Whr3,    // float4 [32][512]
    const float* __restrict__ Whql,    // [16][128]
    const float* __restrict__ hx0, const float* __restrict__ cx0,
    float* __restrict__ stateH, float* __restrict__ stateC,
    const float* __restrict__ Wq, const float* __restrict__ bq,
    const float* __restrict__ thf, const float* __restrict__ thi,
    const float* __restrict__ thg, const float* __restrict__ tho,
    float* __restrict__ out, int t0, int TC)
{
    __shared__ __align__(16) float4 WL[12][512];   // 96 KB: weights j=20..31
    __shared__ __align__(16) float hL[2][152];     // skewed
    __shared__ __align__(16) float WhqL[16][132];
    __shared__ __align__(16) float EZ[2][4][4];

    const int tid  = threadIdx.x;
    const int row0 = blockIdx.x * 2;
    const int ks   = tid & 3;        // k-segment (32 k each)
    const int h    = tid >> 2;       // 0..127: this thread's h column

    // ---- weights j<20 into VGPRs (80 regs), j>=20 into LDS; coalesced ----
    const float4* Wp3 = (const float4*)Whr3;
    float4 wv[20];
    #pragma unroll
    for (int j = 0; j < 20; ++j) wv[j] = Wp3[j * 512 + tid];
    #pragma unroll
    for (int j = 0; j < 20; ++j) PIN4(wv[j]);   // one-time anchor
    #pragma unroll
    for (int j = 0; j < 12; ++j) WL[j][tid] = Wp3[(20 + j) * 512 + tid];

    // ---- stage q-col weights to LDS ----
    #pragma unroll
    for (int j = 0; j < 4; ++j) {
        int i = tid * 4 + j;         // 0..2047
        WhqL[i >> 7][i & 127] = Whql[i];
    }

    // ---- per-thread invariants ----
    const bool isCell = (ks < 2);
    const int  r      = ks & 1;      // cell row for isCell lanes
    float4 wqv = make_float4(0.f, 0.f, 0.f, 0.f);
    float bb = 0.f, cxr = 0.f;
    if (isCell) {
        wqv = *(const float4*)(Wq + h * 4);
        bb  = bq[h];
    }
    // q-side invariants (tid<128): qc=tid>>3, rq=(tid>>2)&1, kseg=tid&3
    int qc = 0, rq = 0, kseg = 0, qw = 0, qg = 0;
    float qcoef = 1.f, qth3 = 0.f;
    if (tid < 128) {
        qc = tid >> 3; rq = (tid >> 2) & 1; kseg = tid & 3;
        qg = qc >> 2;  qw = qc & 3;
        const float* thp = (qg == 0) ? thf : (qg == 1) ? thi : (qg == 2) ? thg : tho;
        qcoef = (qw < 3) ? cosf(thp[qw]) : 1.f;
        qth3  = thp[3];
    }
    if (isCell) {
        const float* hs = (t0 == 0) ? hx0 : stateH;
        const float* cs = (t0 == 0) ? cx0 : stateC;
        hL[r][hsk(h)] = hs[(size_t)(row0 + r) * HH + h];
        cxr           = cs[(size_t)(row0 + r) * HH + h];
    }
    __syncthreads();

    for (int tc = 0; tc < TC; ++tc) {
        const float* zrow = Zx + ((size_t)tc * BB + row0) * NCOL;
        // prefetch (latency hidden under GEMM)
        float zc0 = 0, zc1 = 0, zc2 = 0, zc3 = 0, zqv = 0;
        if (isCell) {
            const float* zp = zrow + (size_t)r * NCOL + h;
            zc0 = zp[0]; zc1 = zp[128]; zc2 = zp[256]; zc3 = zp[384];
        }
        if (tid < 128) zqv = zrow[(size_t)rq * NCOL + 512 + qc];

        // ---- h-GEMM: 4 gate-cols (own h) x 32 k x 2 rows ----
        // f,i from VGPR (wv[0..15]); g: k4<4 VGPR wv[16..19], k4>=4 LDS WL[0..3];
        // o: LDS WL[4..11]. Each 16B LDS weight read feeds 8 FMAs.
        float aF0 = 0, aF1 = 0, aI0 = 0, aI1 = 0, aG0 = 0, aG1 = 0, aO0 = 0, aO1 = 0;
        {
            const float4* h0p = (const float4*)&hL[0][40 * ks];
            const float4* h1p = (const float4*)&hL[1][40 * ks];
            #pragma unroll
            for (int k4 = 0; k4 < 4; ++k4) {
                float4 hv0 = h0p[k4];
                float4 hv1 = h1p[k4];
                float4 wo_ = WL[4 + k4][tid];
                FMA4(aF0, wv[k4],      hv0);  FMA4(aF1, wv[k4],      hv1);
                FMA4(aI0, wv[8 + k4],  hv0);  FMA4(aI1, wv[8 + k4],  hv1);
                FMA4(aG0, wv[16 + k4], hv0);  FMA4(aG1, wv[16 + k4], hv1);
                FMA4(aO0, wo_,         hv0);  FMA4(aO1, wo_,         hv1);
            }
            #pragma unroll
            for (int k4 = 4; k4 < 8; ++k4) {
                float4 hv0 = h0p[k4];
                float4 hv1 = h1p[k4];
                float4 wg_ = WL[k4 - 4][tid];
                float4 wo_ = WL[4 + k4][tid];
                FMA4(aF0, wv[k4],     hv0);  FMA4(aF1, wv[k4],     hv1);
                FMA4(aI0, wv[8 + k4], hv0);  FMA4(aI1, wv[8 + k4], hv1);
                FMA4(aG0, wg_,        hv0);  FMA4(aG1, wg_,        hv1);
                FMA4(aO0, wo_,        hv0);  FMA4(aO1, wo_,        hv1);
            }
        }
        // 2-level butterfly over the 4 k-segment lanes
        #define BRED(v) { v += __shfl_xor(v, 1, 64); v += __shfl_xor(v, 2, 64); }
        BRED(aF0) BRED(aF1) BRED(aI0) BRED(aI1)
        BRED(aG0) BRED(aG1) BRED(aO0) BRED(aO1)
        #undef BRED

        // ---- q side (waves 0-1): angle dots + closed-form E ----
        if (tid < 128) {
            float qa = 0.f;
            const float4* hqp = (const float4*)&hL[rq][40 * kseg];
            #pragma unroll
            for (int k4 = 0; k4 < 8; ++k4) {
                float4 wq4 = *(const float4*)&WhqL[qc][kseg * 32 + 4 * k4];
                FMA4(qa, wq4, hqp[k4]);
            }
            qa += __shfl_xor(qa, 1, 64);
            qa += __shfl_xor(qa, 2, 64);
            float a = zqv + qa;
            float c = __cosf(a);
            int lbase = ((qg & 1) * 4) * 8 + rq * 4;   // lane of wire 0 of this (g,rq)
            float cw0 = __shfl(c, lbase, 64);
            float cw1 = __shfl(c, lbase + 8, 64);
            float cw2 = __shfl(c, lbase + 16, 64);
            float own = (qw == 3) ? __cosf(a + qth3) : c;
            float prod = 1.f;
            if (qw >= 1) prod *= cw0;
            if (qw >= 2) prod *= cw1;
            if (qw == 3) prod *= cw2;
            if (kseg == 0) EZ[rq][qg][qw] = qcoef * prod * own;
        }
        __syncthreads();   // EZ visible; all hL reads done

        // ---- fused cell update ----
        if (isCell) {
            float pf = zc0 + (r ? aF1 : aF0);
            float pi = zc1 + (r ? aI1 : aI0);
            float pg = zc2 + (r ? aG1 : aG0);
            float po = zc3 + (r ? aO1 : aO0);
            float4 Ef = *(const float4*)&EZ[r][0][0];
            float4 Ei = *(const float4*)&EZ[r][1][0];
            float4 Eg = *(const float4*)&EZ[r][2][0];
            float4 Eo = *(const float4*)&EZ[r][3][0];
            float qf = fmaf(Ef.x, wqv.x, fmaf(Ef.y, wqv.y, fmaf(Ef.z, wqv.z, fmaf(Ef.w, wqv.w, bb))));
            float qi = fmaf(Ei.x, wqv.x, fmaf(Ei.y, wqv.y, fmaf(Ei.z, wqv.z, fmaf(Ei.w, wqv.w, bb))));
            float qg2 = fmaf(Eg.x, wqv.x, fmaf(Eg.y, wqv.y, fmaf(Eg.z, wqv.z, fmaf(Eg.w, wqv.w, bb))));
            float qo = fmaf(Eo.x, wqv.x, fmaf(Eo.y, wqv.y, fmaf(Eo.z, wqv.z, fmaf(Eo.w, wqv.w, bb))));
            float f  = sigm(pf)   + sigm(qf);
            float ii = sigm(pi)   + sigm(qi);
            float gg = tanh_f(pg) + tanh_f(qg2);
            float oo = sigm(po)   + sigm(qo);
            float cn = fmaf(f, cxr, ii * gg);
            cxr = cn;
            float hn = oo * tanh_f(cn);
            hL[r][hsk(h)] = hn;
            out[((size_t)(t0 + tc) * BB + row0 + r) * HH + h] = hn;
        }
        __syncthreads();   // h_{t+1} visible
    }

    if (isCell) {
        float hn = hL[r][hsk(h)];
        stateH[(size_t)(row0 + r) * HH + h] = hn;
        stateC[(size_t)(row0 + r) * HH + h] = cxr;
        if (t0 + TC == TT) {
            size_t base = (size_t)TT * BB * HH;
            out[base + (size_t)(row0 + r) * HH + h]                   = hn;
            out[base + (size_t)BB * HH + (size_t)(row0 + r) * HH + h] = cxr;
        }
    }
}

extern "C" void kernel_launch(void* const* d_in, const int* in_sizes, int n_in,
                              void* d_out, int out_size, void* d_ws, size_t ws_size,
                              hipStream_t stream) {
    const float* X   = (const float*)d_in[0];
    const float* hx0 = (const float*)d_in[1];
    const float* cx0 = (const float*)d_in[2];
    const float* Wf  = (const float*)d_in[3];
    const float* bf  = (const float*)d_in[4];
    const float* Wfq = (const float*)d_in[5];
    const float* bfq = (const float*)d_in[6];
    const float* thf = (const float*)d_in[7];
    const float* Wi  = (const float*)d_in[8];
    const float* bi  = (const float*)d_in[9];
    const float* Wiq = (const float*)d_in[10];
    const float* biq = (const float*)d_in[11];
    const float* thi = (const float*)d_in[12];
    const float* Wg  = (const float*)d_in[13];
    const float* bg  = (const float*)d_in[14];
    const float* Wgq = (const float*)d_in[15];
    const float* bgq = (const float*)d_in[16];
    const float* thg = (const float*)d_in[17];
    const float* Wo  = (const float*)d_in[18];
    const float* bo  = (const float*)d_in[19];
    const float* Woq = (const float*)d_in[20];
    const float* boq = (const float*)d_in[21];
    const float* tho = (const float*)d_in[22];
    const float* Wq  = (const float*)d_in[23];
    const float* bq  = (const float*)d_in[24];

    float* ws = (float*)d_ws;
    float* Wxp    = ws;                         // 528*128 = 67584
    float* Whr3   = Wxp + 528 * 128;            // 32*512*4 = 65536
    float* Whql   = Whr3 + 65536;               // 16*128 = 2048
    float* bcatp  = Whql + 2048;                // 576
    float* stateH = bcatp + NCPAD;              // 65536
    float* stateC = stateH + 512 * 128;         // 65536
    float* Zxb    = stateC + 512 * 128;

    size_t fixed_bytes = (size_t)(Zxb - ws) * sizeof(float);
    int TC = 256;
    while (TC > 4 && fixed_bytes + (size_t)TC * 512 * NCOL * 4 > ws_size) TC >>= 1;

    pack_weights<<<(NCOL * KK + 255) / 256, 256, 0, stream>>>(
        Wf, bf, Wfq, bfq, Wi, bi, Wiq, biq, Wg, bg, Wgq, bgq, Wo, bo, Woq, boq,
        Wxp, Whr3, Whql, bcatp);

    for (int t0 = 0; t0 < TT; t0 += TC) {
        xgemm<<<dim3(TC * 512 / P1_BM, NCPAD / P1_BN), 256, 0, stream>>>(
            X + (size_t)t0 * BB * DD, Wxp, bcatp, Zxb);
        qlstm_rec<<<256, 512, 0, stream>>>(
            Zxb, Whr3, Whql, hx0, cx0, stateH, stateC, Wq, bq,
            thf, thi, thg, tho, (float*)d_out, t0, TC);
    }
}

// Round 10
// 774.029 us; speedup vs baseline: 1.0164x; 1.0164x over previous
//
#include <hip/hip_runtime.h>
#include <cmath>

#define TT 256
#define BB 512
#define DD 128
#define HH 128
#define NCOL 528   // 4*H + 16 quantum-angle cols
#define KK 256
#define NCPAD 576  // 9 * 64

// ---------------- weight pack ----------------
// Wxp[528][128]                 : x-half row-major (xgemm staging)
// Whr3 float4[j][t] (j=g*8+k4)  : h-half main cols; thread t=h*4+ks owns cols
//                                 {g*128+h, g=0..3}, k-seg ks (32 k each)
// Whql[16][128]                 : h-half quantum cols (per-task regs in rec)
// bcat[576]
__global__ __launch_bounds__(256) void pack_weights(
    const float* __restrict__ Wf, const float* __restrict__ bf,
    const float* __restrict__ Wfq, const float* __restrict__ bfq,
    const float* __restrict__ Wi, const float* __restrict__ bi,
    const float* __restrict__ Wiq, const float* __restrict__ biq,
    const float* __restrict__ Wg, const float* __restrict__ bg,
    const float* __restrict__ Wgq, const float* __restrict__ bgq,
    const float* __restrict__ Wo, const float* __restrict__ bo,
    const float* __restrict__ Woq, const float* __restrict__ boq,
    float* __restrict__ Wxp, float* __restrict__ Whr3,
    float* __restrict__ Whql, float* __restrict__ bcat)
{
    int idx = blockIdx.x * blockDim.x + threadIdx.x;
    if (idx < NCOL * KK) {
        int c = idx >> 8, k = idx & 255;
        const float* srcW; int cl;
        if (c < 512) { int g = c >> 7; cl = c & 127;
            srcW = (g == 0) ? Wf : (g == 1) ? Wi : (g == 2) ? Wg : Wo; }
        else { int g = (c - 512) >> 2; cl = (c - 512) & 3;
            srcW = (g == 0) ? Wfq : (g == 1) ? Wiq : (g == 2) ? Wgq : Woq; }
        float v = srcW[(size_t)cl * KK + k];
        if (k < 128) Wxp[(size_t)c * 128 + k] = v;
        else {
            int kk = k - 128;
            if (c < 512) {
                int gate = c >> 7, hcol = c & 127;
                int t = hcol * 4 + (kk >> 5);
                int j = gate * 8 + ((kk >> 2) & 7);
                Whr3[((size_t)j * 512 + t) * 4 + (kk & 3)] = v;
            } else {
                Whql[(size_t)(c - 512) * 128 + kk] = v;
            }
        }
    }
    if (idx < NCPAD) {
        float b = 0.f;
        int c = idx;
        if (c < 512) { int g = c >> 7; int cl = c & 127;
            b = (g == 0) ? bf[cl] : (g == 1) ? bi[cl] : (g == 2) ? bg[cl] : bo[cl]; }
        else if (c < NCOL) { int g = (c - 512) >> 2; int cl = (c - 512) & 3;
            b = (g == 0) ? bfq[cl] : (g == 1) ? biq[cl] : (g == 2) ? bgq[cl] : boq[cl]; }
        bcat[c] = b;
    }
}

// ---------------- phase 1: Zx = X @ Wx^T + bcat  (M x 528, K=128) ----------------
#define P1_BM 128
#define P1_BN 64
#define ATP 132
#define BTP 68
__global__ __launch_bounds__(256, 3) void xgemm(
    const float* __restrict__ X, const float* __restrict__ Wxp,
    const float* __restrict__ bcat, float* __restrict__ Zx)
{
    __shared__ float At[64][ATP];
    __shared__ float Bt[64][BTP];
    const int tid = threadIdx.x;
    const int m0 = blockIdx.x * P1_BM;
    const int c0 = blockIdx.y * P1_BN;
    const int tm = tid >> 3;
    const int tn = tid & 7;
    float acc[4][8] = {};

    for (int khf = 0; khf < 2; ++khf) {
        #pragma unroll
        for (int j = 0; j < 8; ++j) {
            int fidx = tid + 256 * j;
            int m = fidx >> 4, k4 = (fidx & 15) * 4;
            float4 v = *(const float4*)(X + (size_t)(m0 + m) * 128 + khf * 64 + k4);
            At[k4 + 0][m] = v.x; At[k4 + 1][m] = v.y; At[k4 + 2][m] = v.z; At[k4 + 3][m] = v.w;
        }
        #pragma unroll
        for (int j = 0; j < 4; ++j) {
            int fidx = tid + 256 * j;
            int c = fidx >> 4, k4 = (fidx & 15) * 4;
            int cg = c0 + c;
            float4 v = make_float4(0.f, 0.f, 0.f, 0.f);
            if (cg < NCOL) v = *(const float4*)(Wxp + (size_t)cg * 128 + khf * 64 + k4);
            Bt[k4 + 0][c] = v.x; Bt[k4 + 1][c] = v.y; Bt[k4 + 2][c] = v.z; Bt[k4 + 3][c] = v.w;
        }
        __syncthreads();
        #pragma unroll 4
        for (int k = 0; k < 64; ++k) {
            float4 a  = *(const float4*)&At[k][tm * 4];
            float4 b0 = *(const float4*)&Bt[k][tn * 8];
            float4 b1 = *(const float4*)&Bt[k][tn * 8 + 4];
            float av[4] = {a.x, a.y, a.z, a.w};
            float bv[8] = {b0.x, b0.y, b0.z, b0.w, b1.x, b1.y, b1.z, b1.w};
            #pragma unroll
            for (int i = 0; i < 4; ++i)
                #pragma unroll
                for (int j = 0; j < 8; ++j)
                    acc[i][j] = fmaf(av[i], bv[j], acc[i][j]);
        }
        __syncthreads();
    }
    int c = c0 + tn * 8;
    if (c < NCOL) {
        float4 ba = *(const float4*)(bcat + c);
        float4 bb = *(const float4*)(bcat + c + 4);
        #pragma unroll
        for (int i = 0; i < 4; ++i) {
            int m = m0 + tm * 4 + i;
            float4 o0, o1;
            o0.x = acc[i][0] + ba.x; o0.y = acc[i][1] + ba.y;
            o0.z = acc[i][2] + ba.z; o0.w = acc[i][3] + ba.w;
            o1.x = acc[i][4] + bb.x; o1.y = acc[i][5] + bb.y;
            o1.z = acc[i][6] + bb.z; o1.w = acc[i][7] + bb.w;
            *(float4*)(Zx + (size_t)m * NCOL + c)     = o0;
            *(float4*)(Zx + (size_t)m * NCOL + c + 4) = o1;
        }
    }
}

// ---------------- phase 2: recurrence ----------------
__device__ __forceinline__ float sigm(float x) { return 1.0f / (1.0f + __expf(-x)); }
__device__ __forceinline__ float tanh_f(float x) {
    float e = __expf(2.f * x);
    return 1.f - 2.f / (e + 1.f);
}

// macro params must NOT be named x/y/z/w
#define FMA4(acc, Wv, Xv) acc = fmaf((Wv).x, (Xv).x, fmaf((Wv).y, (Xv).y, fmaf((Wv).z, (Xv).z, fmaf((Wv).w, (Xv).w, (acc)))))
#define PIN4(Wv) asm volatile("" : "+v"((Wv).x), "+v"((Wv).y), "+v"((Wv).z), "+v"((Wv).w))

// in-quad allreduce via DPP quad_perm (no LDS): 0xB1 = [1,0,3,2] (xor1), 0x4E = [2,3,0,1] (xor2)
#define DPPRED(v) { \
    v += __int_as_float(__builtin_amdgcn_update_dpp(0, __float_as_int(v), 0xB1, 0xF, 0xF, true)); \
    v += __int_as_float(__builtin_amdgcn_update_dpp(0, __float_as_int(v), 0x4E, 0xF, 0xF, true)); }

// skewed h index: the 4 k-segments land on distinct bank quads
__device__ __forceinline__ int hsk(int k) { return k + 8 * (k >> 5); }  // max 151

// 512 threads; waves_per_eu(2,2): 256-VGPR cap.
__global__ __launch_bounds__(512)
__attribute__((amdgpu_waves_per_eu(2, 2)))
void qlstm_rec(
    const float* __restrict__ Zx,      // [TC][512][528]
    const float* __restrict__ Whr3,    // float4 [32][512]
    const float* __restrict__ Whql,    // [16][128]
    const float* __restrict__ hx0, const float* __restrict__ cx0,
    float* __restrict__ stateH, float* __restrict__ stateC,
    const float* __restrict__ Wq, const float* __restrict__ bq,
    const float* __restrict__ thf, const float* __restrict__ thi,
    const float* __restrict__ thg, const float* __restrict__ tho,
    float* __restrict__ out, int t0, int TC)
{
    __shared__ __align__(16) float hL[2][152];     // skewed
    __shared__ __align__(16) float cEd[2][20];     // per (r, qc): d = (w<3 ? cos(th_w)*c : cos(a3+th3))
    __shared__ __align__(16) float cEc[2][20];     // per (r, qc): raw c = cos(a)

    const int tid  = threadIdx.x;
    const int row0 = blockIdx.x * 2;
    const int ks   = tid & 3;        // k-segment (32 k each)
    const int h    = tid >> 2;       // 0..127: this thread's h column

    // ---- main weights into registers: 32 f4 (128 regs), coalesced ----
    const float4* Wp3 = (const float4*)Whr3;
    float4 wv[32];
    #pragma unroll
    for (int j = 0; j < 32; ++j) wv[j] = Wp3[j * 512 + tid];
    #pragma unroll
    for (int j = 0; j < 32; ++j) PIN4(wv[j]);   // one-time anchor

    // ---- per-thread invariants ----
    const bool isCell = (ks < 2);
    const int  r      = ks & 1;
    float4 wqv = make_float4(0.f, 0.f, 0.f, 0.f);
    float bb = 0.f, cxr = 0.f;
    if (isCell) {
        wqv = *(const float4*)(Wq + h * 4);
        bb  = bq[h];
    }
    // q-tasks: one per quad at (tid&15)<4 -> 32 tasks spread over all 8 waves
    const bool isQ = (tid & 15) < 4;
    const int qi = tid >> 4;         // 0..31
    const int rq = qi & 1, qc = qi >> 1;        // qc = qg*4+qw
    const int qg = qc >> 2, qw = qc & 3;
    float qcoef = 1.f, qth3 = 0.f;
    float4 qw4[8] = {};
    if (isQ) {
        const float* thp = (qg == 0) ? thf : (qg == 1) ? thi : (qg == 2) ? thg : tho;
        qcoef = (qw < 3) ? cosf(thp[qw]) : 1.f;
        qth3  = thp[3];
        const float4* qp = (const float4*)(Whql + (size_t)qc * 128 + ks * 32);
        #pragma unroll
        for (int j = 0; j < 8; ++j) qw4[j] = qp[j];
    }
    if (isCell) {
        const float* hs = (t0 == 0) ? hx0 : stateH;
        const float* cs = (t0 == 0) ? cx0 : stateC;
        hL[r][hsk(h)] = hs[(size_t)(row0 + r) * HH + h];
        cxr           = cs[(size_t)(row0 + r) * HH + h];
    }
    __syncthreads();

    for (int tc = 0; tc < TC; ++tc) {
        const float* zrow = Zx + ((size_t)tc * BB + row0) * NCOL;
        // prefetch (latency hidden under GEMM)
        float zc0 = 0, zc1 = 0, zc2 = 0, zc3 = 0, zqv = 0;
        if (isCell) {
            const float* zp = zrow + (size_t)r * NCOL + h;
            zc0 = zp[0]; zc1 = zp[128]; zc2 = zp[256]; zc3 = zp[384];
        }
        if (isQ) zqv = zrow[(size_t)rq * NCOL + 512 + qc];

        // ---- h-GEMM: 4 gate-cols (own h) x 32 k x 2 rows; q-dot rides along ----
        float aF0 = 0, aF1 = 0, aI0 = 0, aI1 = 0, aG0 = 0, aG1 = 0, aO0 = 0, aO1 = 0;
        float qa = 0.f;
        {
            const float4* h0p = (const float4*)&hL[0][40 * ks];
            const float4* h1p = (const float4*)&hL[1][40 * ks];
            #pragma unroll
            for (int k4 = 0; k4 < 8; ++k4) {
                float4 hv0 = h0p[k4];
                float4 hv1 = h1p[k4];
                FMA4(aF0, wv[k4],      hv0);  FMA4(aF1, wv[k4],      hv1);
                FMA4(aI0, wv[8 + k4],  hv0);  FMA4(aI1, wv[8 + k4],  hv1);
                FMA4(aG0, wv[16 + k4], hv0);  FMA4(aG1, wv[16 + k4], hv1);
                FMA4(aO0, wv[24 + k4], hv0);  FMA4(aO1, wv[24 + k4], hv1);
                float4 hq;
                hq.x = rq ? hv1.x : hv0.x; hq.y = rq ? hv1.y : hv0.y;
                hq.z = rq ? hv1.z : hv0.z; hq.w = rq ? hv1.w : hv0.w;
                FMA4(qa, qw4[k4], hq);    // qw4==0 on non-task lanes
            }
        }
        // in-quad allreduce via DPP (VALU only, no LDS)
        DPPRED(aF0) DPPRED(aF1) DPPRED(aI0) DPPRED(aI1)
        DPPRED(aG0) DPPRED(aG1) DPPRED(aO0) DPPRED(aO1)
        DPPRED(qa)

        // ---- q-tasks: angle -> cosines published to LDS ----
        if (isQ) {
            float a = zqv + qa;
            float c = __cosf(a);
            float dval = (qw < 3) ? qcoef * c : __cosf(a + qth3);
            if (ks == 0) {
                cEd[rq][qc] = dval;
                cEc[rq][qc] = c;
            }
        }
        __syncthreads();   // cE* visible; all hL reads done

        // ---- fused cell update: assemble E from cosine prefix products ----
        if (isCell) {
            float pf = zc0 + (r ? aF1 : aF0);
            float pi = zc1 + (r ? aI1 : aI0);
            float pg = zc2 + (r ? aG1 : aG0);
            float po = zc3 + (r ? aO1 : aO0);
            float qz[4];
            #pragma unroll
            for (int g = 0; g < 4; ++g) {
                float4 dv = *(const float4*)&cEd[r][g * 4];
                float4 cv = *(const float4*)&cEc[r][g * 4];
                float c01  = cv.x * cv.y;
                float c012 = c01 * cv.z;
                qz[g] = fmaf(dv.x, wqv.x,
                        fmaf(dv.y * cv.x, wqv.y,
                        fmaf(dv.z * c01, wqv.z,
                        fmaf(dv.w * c012, wqv.w, bb))));
            }
            float f  = sigm(pf)   + sigm(qz[0]);
            float ii = sigm(pi)   + sigm(qz[1]);
            float gg = tanh_f(pg) + tanh_f(qz[2]);
            float oo = sigm(po)   + sigm(qz[3]);
            float cn = fmaf(f, cxr, ii * gg);
            cxr = cn;
            float hn = oo * tanh_f(cn);
            hL[r][hsk(h)] = hn;
            out[((size_t)(t0 + tc) * BB + row0 + r) * HH + h] = hn;
        }
        __syncthreads();   // h_{t+1} visible
    }

    if (isCell) {
        float hn = hL[r][hsk(h)];
        stateH[(size_t)(row0 + r) * HH + h] = hn;
        stateC[(size_t)(row0 + r) * HH + h] = cxr;
        if (t0 + TC == TT) {
            size_t base = (size_t)TT * BB * HH;
            out[base + (size_t)(row0 + r) * HH + h]                   = hn;
            out[base + (size_t)BB * HH + (size_t)(row0 + r) * HH + h] = cxr;
        }
    }
}

extern "C" void kernel_launch(void* const* d_in, const int* in_sizes, int n_in,
                              void* d_out, int out_size, void* d_ws, size_t ws_size,
                              hipStream_t stream) {
    const float* X   = (const float*)d_in[0];
    const float* hx0 = (const float*)d_in[1];
    const float* cx0 = (const float*)d_in[2];
    const float* Wf  = (const float*)d_in[3];
    const float* bf  = (const float*)d_in[4];
    const float* Wfq = (const float*)d_in[5];
    const float* bfq = (const float*)d_in[6];
    const float* thf = (const float*)d_in[7];
    const float* Wi  = (const float*)d_in[8];
    const float* bi  = (const float*)d_in[9];
    const float* Wiq = (const float*)d_in[10];
    const float* biq = (const float*)d_in[11];
    const float* thi = (const float*)d_in[12];
    const float* Wg  = (const float*)d_in[13];
    const float* bg  = (const float*)d_in[14];
    const float* Wgq = (const float*)d_in[15];
    const float* bgq = (const float*)d_in[16];
    const float* thg = (const float*)d_in[17];
    const float* Wo  = (const float*)d_in[18];
    const float* bo  = (const float*)d_in[19];
    const float* Woq = (const float*)d_in[20];
    const float* boq = (const float*)d_in[21];
    const float* tho = (const float*)d_in[22];
    const float* Wq  = (const float*)d_in[23];
    const float* bq  = (const float*)d_in[24];

    float* ws = (float*)d_ws;
    float* Wxp    = ws;                         // 528*128 = 67584
    float* Whr3   = Wxp + 528 * 128;            // 32*512*4 = 65536
    float* Whql   = Whr3 + 65536;               // 16*128 = 2048
    float* bcatp  = Whql + 2048;                // 576
    float* stateH = bcatp + NCPAD;              // 65536
    float* stateC = stateH + 512 * 128;         // 65536
    float* Zxb    = stateC + 512 * 128;

    size_t fixed_bytes = (size_t)(Zxb - ws) * sizeof(float);
    int TC = 256;
    while (TC > 4 && fixed_bytes + (size_t)TC * 512 * NCOL * 4 > ws_size) TC >>= 1;

    pack_weights<<<(NCOL * KK + 255) / 256, 256, 0, stream>>>(
        Wf, bf, Wfq, bfq, Wi, bi, Wiq, biq, Wg, bg, Wgq, bgq, Wo, bo, Woq, boq,
        Wxp, Whr3, Whql, bcatp);

    for (int t0 = 0; t0 < TT; t0 += TC) {
        xgemm<<<dim3(TC * 512 / P1_BM, NCPAD / P1_BN), 256, 0, stream>>>(
            X + (size_t)t0 * BB * DD, Wxp, bcatp, Zxb);
        qlstm_rec<<<256, 512, 0, stream>>>(
            Zxb, Whr3, Whql, hx0, cx0, stateH, stateC, Wq, bq,
            thf, thi, thg, tho, (float*)d_out, t0, TC);
    }
}